// Round 3
// baseline (292.756 us; speedup 1.0000x reference)
//
#include <hip/hip_runtime.h>

// KernelAggregation: per-sample mixed 3x3 SAME conv, implicit GEMM via bf16 MFMA.
// ws: [0, 2359296) = wmix bf16 [32][9 taps][64 co][64 ci]; [2359296, +8192) = bmix f32 [32][64].
// R2: K-split (2 halves of 32 ci) -> 33.5 KB LDS -> 4 blocks/CU; packed b32 stage
// writes; operands swapped (A=X, B=W) so epilogue stores are dwordx4.

#define DIM 64
#define BATCH 32
#define HH 128
#define WW 128
#define NK 4

typedef __attribute__((ext_vector_type(4))) float f32x4;
typedef __attribute__((ext_vector_type(8))) short bf16x8;
typedef __attribute__((ext_vector_type(8))) unsigned short ushort8;

static __device__ __forceinline__ unsigned short f2bf(float f) {
    union { float f; unsigned u; } v; v.f = f;
    unsigned r = v.u + 0x7fffu + ((v.u >> 16) & 1u);   // RNE, inputs finite
    return (unsigned short)(r >> 16);
}

// One wave per (b, co): coalesced read of w[k][co][:,:], mix in registers,
// LDS transpose (ci,tap)->(tap,ci), coalesced bf16 write to wmix[b][tap][co][ci].
__global__ __launch_bounds__(256) void mix_weights(
    const float* __restrict__ w, const float* __restrict__ att,
    unsigned short* __restrict__ wmix) {
    __shared__ float tr[4][576];
    int wave = threadIdx.x >> 6, lane = threadIdx.x & 63;
    int idx = blockIdx.x * 4 + wave;               // 2048 (b,co) pairs
    int b = idx >> 6, co = idx & 63;
    float a[NK];
    #pragma unroll
    for (int k = 0; k < NK; ++k) a[k] = att[b * NK + k];
    float s[9];
    #pragma unroll
    for (int t = 0; t < 9; ++t) s[t] = 0.f;
    #pragma unroll
    for (int k = 0; k < NK; ++k) {
        const float* wp = w + (size_t)(k * DIM + co) * 576;
        #pragma unroll
        for (int t = 0; t < 9; ++t)
            s[t] += a[k] * wp[t * 64 + lane];      // element e = t*64+lane = ci*9+tap
    }
    #pragma unroll
    for (int t = 0; t < 9; ++t) tr[wave][t * 64 + lane] = s[t];
    __syncthreads();
    #pragma unroll
    for (int t = 0; t < 9; ++t) {
        float v = tr[wave][lane * 9 + t];          // (tap=t, ci=lane)
        wmix[(((size_t)b * 9 + t) * DIM + co) * DIM + lane] = f2bf(v);
    }
}

__global__ __launch_bounds__(256) void mix_bias(
    const float* __restrict__ bias, const float* __restrict__ att,
    float* __restrict__ bmix) {
    int idx = blockIdx.x * 256 + threadIdx.x;      // 2048
    if (idx >= BATCH * DIM) return;
    int b = idx >> 6, co = idx & 63;
    float s = 0.f;
    for (int k = 0; k < NK; ++k) s += att[b * NK + k] * bias[k * DIM + co];
    bmix[idx] = s;
}

// Xs[r][c][ci0..31] bf16, 64B rows; group(8ci) swizzled by (c>>2)&3.
// Ws[buf][co][ci0..31], group swizzled by (co>>1)&3.
#define XIDX(r, c, grp, off) (((r) * 66 + (c)) * 32 + (((grp) ^ (((c) >> 2) & 3)) << 3) + (off))
#define WIDX(co, grp) ((co) * 32 + (((grp) ^ (((co) >> 1) & 3)) << 3))

__global__ __launch_bounds__(256, 4) void conv_mfma(
    const float* __restrict__ x, const unsigned short* __restrict__ wmix,
    const float* __restrict__ bmix, float* __restrict__ out) {

    __shared__ unsigned short Xs[6 * 66 * 32];     // 25,344 B
    __shared__ unsigned short Ws[2][64 * 32];      //  8,192 B  (total 33,536 -> 4 blocks/CU)

    int bid = blockIdx.x;
    int b   = bid >> 6;
    int r6  = bid & 63;
    int h0  = (r6 >> 1) * 4;
    int w0  = (r6 & 1) * 64;

    int tid  = threadIdx.x;
    int wave = tid >> 6, lane = tid & 63;
    int l15  = lane & 15, q = lane >> 4;

    // weight chunk: thread -> (co = tid>>2, logical group g = tid&3), 16B per tap-half
    const int wco = tid >> 2, wg = tid & 3;
    const unsigned short* wsrc = wmix + (size_t)b * 9 * 4096 + wco * 64 + wg * 8;
    const int wdst = WIDX(wco, wg);
    ushort8 wr = *(const ushort8*)(wsrc);          // t=0: tap0, half0

    // bias: epilogue co = nt*16 + l15
    float biasr[4];
    #pragma unroll
    for (int nt = 0; nt < 4; ++nt) biasr[nt] = bmix[b * DIM + nt * 16 + l15];

    // X stage assignment: per row, thread -> ci-pair P = tid>>4, col-quad c4 = tid&15
    const int P = tid >> 4, c4 = tid & 15;
    const int xg = P >> 2, xoff = 2 * (P & 3);     // group, short-offset of ci pair

    f32x4 acc[4][4];
    f32x4 zero = {0.f, 0.f, 0.f, 0.f};
    #pragma unroll
    for (int mt = 0; mt < 4; ++mt)
        #pragma unroll
        for (int nt = 0; nt < 4; ++nt) acc[mt][nt] = zero;

    // ---------------- X staging for one ci-half ----------------
    auto stage_x = [&](int half) {
        #pragma unroll
        for (int r2 = 0; r2 < 6; r2 += 2) {
            f32x4 v[2][2];
            #pragma unroll
            for (int dr = 0; dr < 2; ++dr) {
                int r = r2 + dr, hin = h0 - 1 + r;
                bool ok = (hin >= 0) && (hin < HH);     // wave-uniform
                int ci = half * 32 + 2 * P;
                const float* xp = &x[(((size_t)b * DIM + ci) * HH + hin) * WW + w0 + c4 * 4];
                v[dr][0] = zero; v[dr][1] = zero;
                if (ok) { v[dr][0] = *(const f32x4*)xp; v[dr][1] = *(const f32x4*)(xp + HH * WW); }
            }
            #pragma unroll
            for (int dr = 0; dr < 2; ++dr) {
                int r = r2 + dr;
                #pragma unroll
                for (int j = 0; j < 4; ++j) {
                    int c = c4 * 4 + 1 + j;
                    unsigned pk = (unsigned)f2bf(v[dr][0][j]) |
                                  ((unsigned)f2bf(v[dr][1][j]) << 16);
                    *(unsigned*)&Xs[XIDX(r, c, xg, xoff)] = pk;
                }
            }
        }
        // edge cols c=0 (win=w0-1), c=65 (win=w0+64): 2 x 6r x 32ci = 384 items
        #pragma unroll
        for (int e = 0; e < 2; ++e) {
            int idx = e * 256 + tid;
            if (idx < 384) {
                int edge = idx >= 192;
                int rem  = idx - edge * 192;
                int ci   = rem & 31, r = rem >> 5;
                int hin  = h0 - 1 + r;
                int win  = edge ? (w0 + 64) : (w0 - 1);
                float vv = 0.f;
                if (hin >= 0 && hin < HH && win >= 0 && win < WW)
                    vv = x[(((size_t)b * DIM + half * 32 + ci) * HH + hin) * WW + win];
                int c = edge ? 65 : 0;
                Xs[XIDX(r, c, ci >> 3, ci & 7)] = f2bf(vv);
            }
        }
    };

    stage_x(0);
    *(ushort8*)&Ws[0][wdst] = wr;                  // tap0 half0
    wr = *(const ushort8*)(wsrc + 4096);           // t=1: tap1 half0
    __syncthreads();

    #pragma unroll
    for (int t = 0; t < 18; ++t) {
        const int tap = (t < 9) ? t : t - 9;
        const int buf = t & 1;
        if (t < 17) {                              // stage weights for t+1
            *(ushort8*)&Ws[buf ^ 1][wdst] = wr;
            if (t < 16) {                          // prefetch t+2
                int tn = t + 2;
                int tapn = (tn < 9) ? tn : tn - 9;
                int halfn = (tn < 9) ? 0 : 1;
                wr = *(const ushort8*)(wsrc + tapn * 4096 + halfn * 32);
            }
        }
        const int kh = tap / 3, kw = tap - kh * 3;
        const int r = wave + kh;
        bf16x8 af[4], bfr[4];
        #pragma unroll
        for (int mt = 0; mt < 4; ++mt) {           // A = X: m = w-col
            int c = mt * 16 + l15 + kw;
            af[mt] = *(const bf16x8*)&Xs[XIDX(r, c, q, 0)];
        }
        #pragma unroll
        for (int nt = 0; nt < 4; ++nt) {           // B = W: n = co
            int co = nt * 16 + l15;
            bfr[nt] = *(const bf16x8*)&Ws[buf][WIDX(co, q)];
        }
        #pragma unroll
        for (int mt = 0; mt < 4; ++mt)
            #pragma unroll
            for (int nt = 0; nt < 4; ++nt)
                acc[mt][nt] = __builtin_amdgcn_mfma_f32_16x16x32_bf16(
                    af[mt], bfr[nt], acc[mt][nt], 0, 0, 0);
        if (t == 8) {                              // swap Xs to ci-half 1
            __syncthreads();
            stage_x(1);
        }
        __syncthreads();
    }

    // epilogue: C/D col = lane&15 = co, row = q*4+rg = w-within-tile
    int h = h0 + wave;
    #pragma unroll
    for (int nt = 0; nt < 4; ++nt) {
        int co = nt * 16 + l15;
        float* op = &out[(((size_t)b * DIM + co) * HH + h) * WW + w0 + q * 4];
        #pragma unroll
        for (int mt = 0; mt < 4; ++mt) {
            f32x4 vv = acc[mt][nt];
            vv[0] += biasr[nt]; vv[1] += biasr[nt];
            vv[2] += biasr[nt]; vv[3] += biasr[nt];
            *(f32x4*)(op + mt * 16) = vv;
        }
    }
}

extern "C" void kernel_launch(void* const* d_in, const int* in_sizes, int n_in,
                              void* d_out, int out_size, void* d_ws, size_t ws_size,
                              hipStream_t stream) {
    const float* x   = (const float*)d_in[0];
    const float* att = (const float*)d_in[1];
    const float* wgt = (const float*)d_in[2];
    const float* bia = (const float*)d_in[3];
    float* out = (float*)d_out;

    unsigned short* wmix = (unsigned short*)d_ws;            // 2,359,296 B
    float* bmix = (float*)((char*)d_ws + 2359296);           //     8,192 B

    mix_weights<<<512, 256, 0, stream>>>(wgt, att, wmix);
    mix_bias<<<8, 256, 0, stream>>>(bia, att, bmix);
    conv_mfma<<<2048, 256, 0, stream>>>(x, wmix, bmix, out);
}